// Round 10
// baseline (2211.151 us; speedup 1.0000x reference)
//
#include <hip/hip_runtime.h>

// ---------------------------------------------------------------------------
// AppUsageFEDformer forward on MI355X (gfx950).
// embed -> 2x [Wq gemm(->qT bf16) -> DFT-GEMM -> mix -> iDFT-GEMM ->
//              Wo gemm(+res) -> decomp -> conv1(relu) -> conv2(+res) -> decomp]
//          -> layernorm(+L-mean sub) -> last-token concat -> proj gemm.
// R9->R10: (1) bf16 activation chain everywhere (t1/x1/t2/x2); Ax/Bs fp32
// buffers deleted (-128MB ws, ~-400MB HBM); res input to GEMM is bf16 now.
// (2) k_gemm = R8's 2-deep register pipeline + __launch_bounds__(256,2):
// spill was the R8 killer (160 regs vs 512/3 budget); at 2 waves/EU budget
// is 256 -> no spill, loads fly ~2 iters before their ds_write vmcnt wait.
// (3) k_decomp: bf16 io + XCD-grouped block swizzle (all chunks of batch b
// on XCD b%8, temporally clustered) so the 57/32-row window overlap hits L2
// (R9: FETCH 118MB = 1.84x unique rows, chunks scattered across XCDs).
// ---------------------------------------------------------------------------

typedef unsigned short u16;
typedef float f32x4 __attribute__((ext_vector_type(4)));
typedef __bf16 bf16x8 __attribute__((ext_vector_type(8)));

__device__ __forceinline__ u16 f2b(float f) {
  unsigned u = __float_as_uint(f);
  return (u16)((u + 0x7FFFu + ((u >> 16) & 1u)) >> 16);
}
__device__ __forceinline__ float b2f(u16 v) {
  return __uint_as_float((unsigned)v << 16);
}
__device__ __forceinline__ f32x4 b4f(ushort4 v) {
  f32x4 r;
  r.x = b2f(v.x); r.y = b2f(v.y); r.z = b2f(v.z); r.w = b2f(v.w);
  return r;
}

// ---------------- bf16 MFMA GEMM:  C = A(MxK) * B(NxK)^T (+bias)(+res)(relu)
// 128x128 tile, BK=32.  Thread t stages 16B of A and B rows r0=t>>2,
// r0+64 (coalesced 1KB/wave) -> VGPR (2 register sets, loads issued 2
// iterations ahead) -> ds_write w/ XOR bank swizzle -> one barrier/iter
// (drains lgkm only).  launch_bounds(256,2): 256-reg budget, no spill.
// res (residual) is bf16.
template<bool BIAS, bool RELU, bool RES, bool OUTBF16, bool GUARD, bool TRANS,
         bool SWZ>
__global__ __launch_bounds__(256, 2)
void k_gemm(const u16* __restrict__ A, const u16* __restrict__ B,
            const float* __restrict__ bias, const u16* __restrict__ res,
            float* __restrict__ Cf, u16* __restrict__ Cb,
            int M, int N, int K,
            long zA, long zB, long zC, int nbn, int nbm)
{
  __shared__ __align__(16) u16 sA[2][128 * 32];
  __shared__ __align__(16) u16 sB[2][128 * 32];
  const int tid = threadIdx.x;
  const int wave = tid >> 6, lane = tid & 63;
  int bn, bm;
  if (SWZ) {
    int bid = blockIdx.x;
    int xcd = bid & 7, loc = bid >> 3;
    bn = loc % nbn;
    bm = xcd * (nbm >> 3) + loc / nbn;
  } else {
    bn = blockIdx.x;
    bm = blockIdx.y;
  }
  const int bz = blockIdx.z;
  const int wm = (wave >> 1) * 64, wn = (wave & 1) * 64;

  A += (size_t)bz * zA;
  B += (size_t)bz * zB;

  const int r0 = tid >> 2;              // row 0..63 (row1 = r0+64)
  const int lg = tid & 3;               // logical 16B group
  const int ps = lg ^ ((r0 >> 1) & 3);  // physical group (same for r0,r0+64)
  int gmA0 = bm * 128 + r0, gmA1 = gmA0 + 64;
  int gnB0 = bn * 128 + r0, gnB1 = gnB0 + 64;
  if (GUARD) {
    gmA0 = gmA0 < M ? gmA0 : M - 1;
    gmA1 = gmA1 < M ? gmA1 : M - 1;
    gnB0 = gnB0 < N ? gnB0 : N - 1;
    gnB1 = gnB1 < N ? gnB1 : N - 1;
  }
  const size_t rb = (size_t)K * 2;
  const char* pa0 = (const char*)A + (size_t)gmA0 * rb + lg * 16;
  const char* pa1 = (const char*)A + (size_t)gmA1 * rb + lg * 16;
  const char* pb0 = (const char*)B + (size_t)gnB0 * rb + lg * 16;
  const char* pb1 = (const char*)B + (size_t)gnB1 * rb + lg * 16;
  const int w0 = r0 * 32 + ps * 8;      // u16 offset in tile; row1 at +2048

  f32x4 acc[4][4];
  const f32x4 z = {0.f, 0.f, 0.f, 0.f};
#pragma unroll
  for (int i = 0; i < 4; ++i)
#pragma unroll
    for (int j = 0; j < 4; ++j) acc[i][j] = z;

  const int r = lane & 15, qd = lane >> 4;
  const int pA = (qd ^ ((lane >> 1) & 3)) * 8;   // fragment physical group
  const int nk = K >> 5;

  uint4 va0[2], va1[2], vb0[2], vb1[2];
  auto gload = [&](int kt, int s) {
    const size_t ko = (size_t)kt * 64;
    va0[s] = *(const uint4*)(pa0 + ko);
    va1[s] = *(const uint4*)(pa1 + ko);
    vb0[s] = *(const uint4*)(pb0 + ko);
    vb1[s] = *(const uint4*)(pb1 + ko);
  };
  auto commit = [&](int pg, int s) {
    *(uint4*)&sA[pg][w0]        = va0[s];
    *(uint4*)&sA[pg][w0 + 2048] = va1[s];
    *(uint4*)&sB[pg][w0]        = vb0[s];
    *(uint4*)&sB[pg][w0 + 2048] = vb1[s];
  };
  auto domfma = [&](int pg) {
    bf16x8 af[4], bg[4];
#pragma unroll
    for (int mi = 0; mi < 4; ++mi)
      af[mi] = *(const bf16x8*)&sA[pg][(wm + mi * 16 + r) * 32 + pA];
#pragma unroll
    for (int ni = 0; ni < 4; ++ni)
      bg[ni] = *(const bf16x8*)&sB[pg][(wn + ni * 16 + r) * 32 + pA];
#pragma unroll
    for (int mi = 0; mi < 4; ++mi)
#pragma unroll
      for (int ni = 0; ni < 4; ++ni)
        acc[mi][ni] = __builtin_amdgcn_mfma_f32_16x16x32_bf16(
            af[mi], bg[ni], acc[mi][ni], 0, 0, 0);
  };

  gload(0, 0);
  if (nk > 1) gload(1, 1);
  for (int kt = 0; kt < nk; kt += 2) {
    commit(0, 0);
    if (kt + 2 < nk) gload(kt + 2, 0);
    __syncthreads();
    domfma(0);
    if (kt + 1 < nk) {
      commit(1, 1);
      if (kt + 3 < nk) gload(kt + 3, 1);
      __syncthreads();
      domfma(1);
    }
  }

  if (Cf) Cf += (size_t)bz * zC;
  if (Cb) Cb += (size_t)bz * zC;
#pragma unroll
  for (int mi = 0; mi < 4; ++mi) {
#pragma unroll
    for (int ni = 0; ni < 4; ++ni) {
#pragma unroll
      for (int e = 0; e < 4; ++e) {
        int gm = bm * 128 + wm + mi * 16 + qd * 4 + e;  // C/D: row=quad*4+reg
        int gn = bn * 128 + wn + ni * 16 + r;           //       col=lane&15
        if (GUARD && (gm >= M || gn >= N)) continue;
        float v = acc[mi][ni][e];
        if (BIAS) v += bias[gn];
        if (RES)  v += b2f(res[(size_t)gm * N + gn]);
        if (RELU) v = v > 0.f ? v : 0.f;
        size_t oi = TRANS ? ((size_t)gn * M + gm) : ((size_t)gm * N + gn);
        if (OUTBF16) Cb[oi] = f2b(v);
        else         Cf[oi] = v;
      }
    }
  }
}

// ---------------- misc small kernels ----------------
__global__ void k_basis(u16* __restrict__ dftB, u16* __restrict__ Binv)
{
  int id = blockIdx.x * 256 + threadIdx.x;  // 32768
  if (id >= 32768) return;
  {
    int m = id >> 9, l = id & 511;
    int mm = m & 31;
    float ang = (float)((l * mm) & 511) * (6.283185307179586f / 512.f);
    float s, c;
    __sincosf(ang, &s, &c);
    dftB[id] = f2b(m < 32 ? c : -s);
  }
  {
    int l = id >> 6, m = id & 63;
    int mm = m & 31;
    float ang = (float)((l * mm) & 511) * (6.283185307179586f / 512.f);
    float s, c;
    __sincosf(ang, &s, &c);
    float v;
    if (m < 32) v = (m == 0 ? 1.f : 2.f) * (1.f / 512.f) * c;
    else        v = (mm == 0 ? 0.f : (-2.f / 512.f) * s);
    Binv[id] = f2b(v);
  }
}

__global__ void k_convert(const float* __restrict__ in, u16* __restrict__ out, int n)
{
  int id = blockIdx.x * 256 + threadIdx.x;
  if (id < n) out[id] = f2b(in[id]);
}

__global__ void k_convproj(const float* __restrict__ w, u16* __restrict__ o)
{
  int id = blockIdx.x * 256 + threadIdx.x;  // 10000*544
  if (id >= 10000 * 544) return;
  int n = id / 544, k = id % 544;
  o[id] = f2b(k < 536 ? w[(size_t)n * 536 + k] : 0.f);
}

// weight transpose for mode mix: wrT[((l*8+h)*32+m)][i][o], LDS pad 33.
__global__ void k_transp(const float* __restrict__ wr, const float* __restrict__ wi,
                         float* __restrict__ wrT, float* __restrict__ wiT)
{
  __shared__ float tr[64 * 33], ti[64 * 33];
  int blk = blockIdx.x;            // (l*8+h)*64+i, 1024 blocks
  int t = threadIdx.x;
  int lh = blk >> 6, i = blk & 63;
  const size_t src = (size_t)blk * 2048;   // o*32+m slab
#pragma unroll
  for (int p = 0; p < 8; ++p) {
    int id = p * 256 + t;
    int o = id >> 5, m = id & 31;
    tr[o * 33 + m] = wr[src + id];
    ti[o * 33 + m] = wi[src + id];
  }
  __syncthreads();
#pragma unroll
  for (int p = 0; p < 8; ++p) {
    int id = p * 256 + t;
    int m = id >> 6, o = id & 63;
    size_t dst = ((size_t)(lh * 32 + m) * 64 + i) * 64 + o;
    wrT[dst] = tr[o * 33 + m];
    wiT[dst] = ti[o * 33 + m];
  }
}

__global__ void k_embed(const int* __restrict__ xapp, const float* __restrict__ xtime,
                        const float* __restrict__ emb, const float* __restrict__ tw,
                        const float* __restrict__ tb, u16* __restrict__ xb)
{
  int id = blockIdx.x * 256 + threadIdx.x;  // B*L*128 (float4 lanes)
  int j = id & 127, bl = id >> 7;
  float4 e = ((const float4*)emb)[(size_t)xapp[bl] * 128 + j];
  float t = xtime[bl];
  float4 w4 = ((const float4*)tw)[j];
  float4 b4 = ((const float4*)tb)[j];
  ushort4 o;
  o.x = f2b(e.x + t * w4.x + b4.x);
  o.y = f2b(e.y + t * w4.y + b4.y);
  o.z = f2b(e.z + t * w4.z + b4.z);
  o.w = f2b(e.w + t * w4.w + b4.w);
  ((ushort4*)xb)[id] = o;
}

// mode mix: coef[b*512 + h*64+o][m](Re) / [32+m](Im), bf16 A-operand.
__global__ __launch_bounds__(256)
void k_mix(const float* __restrict__ spec, const float* __restrict__ wrT,
           const float* __restrict__ wiT, u16* __restrict__ Ab)
{
  __shared__ float swr[4096], swi[4096];   // [i*64+o]
  __shared__ float sre[4][64], sim[4][64]; // [bsub][i]
  int hm = blockIdx.x;                     // h*32+m
  int bg = blockIdx.y;                     // 0..3
  int h = hm >> 5, m = hm & 31, t = threadIdx.x;
  const float* wrb = wrT + (size_t)hm * 4096;
  const float* wib = wiT + (size_t)hm * 4096;
#pragma unroll
  for (int p = 0; p < 16; ++p) {
    int id = p * 256 + t;
    swr[id] = wrb[id];
    swi[id] = wib[id];
  }
  int o = t & 63, bsub = t >> 6;
  for (int b0 = 0; b0 < 16; b0 += 4) {
    __syncthreads();
    int b = bg * 16 + b0 + bsub;
    const float* spb = spec + (size_t)b * 32768;
    sre[bsub][o] = spb[m * 512 + h * 64 + o];
    sim[bsub][o] = spb[(32 + m) * 512 + h * 64 + o];
    __syncthreads();
    float aR = 0.f, aI = 0.f;
#pragma unroll 8
    for (int i = 0; i < 64; ++i) {
      float xr = sre[bsub][i], xi = sim[bsub][i];
      float wrv = swr[i * 64 + o], wiv = swi[i * 64 + o];
      aR += xr * wrv - xi * wiv;
      aI += xr * wiv + xi * wrv;
    }
    size_t row = (size_t)b * 512 + h * 64 + o;
    Ab[row * 64 + m] = f2b(aR);
    Ab[row * 64 + 32 + m] = f2b(aI);
  }
}

// series_decomp: out = x - movavg_25(x), edge-padded.  bf16 in/out, fp32
// accumulate.  XCD-grouped: all 8 blocks of batch b run on XCD b%8,
// temporally clustered, so chunk-window overlap hits that XCD's L2.
__global__ void k_decomp(const u16* __restrict__ in, u16* __restrict__ outb)
{
  int blk = blockIdx.x;                 // 512 blocks
  int j = blk >> 3;
  int b = (blk & 7) + 8 * (j >> 3);     // xcd = b%8
  int ck = (j & 7) * 2 + (threadIdx.x >> 7);
  int d4 = threadIdx.x & 127;
  const ushort4* xb = (const ushort4*)(in + (size_t)b * 262144) + d4;
  ushort4* ob = (ushort4*)(outb + (size_t)b * 262144) + d4;
  int l0 = ck * 32;
  f32x4 sum = {0.f, 0.f, 0.f, 0.f};
#pragma unroll
  for (int jj = -12; jj <= 12; ++jj) {
    int idx = l0 + jj;
    idx = idx < 0 ? 0 : idx;
    sum += b4f(xb[idx * 128]);
  }
#pragma unroll 4
  for (int l = l0; l < l0 + 32; ++l) {
    f32x4 xv = b4f(xb[l * 128]);
    f32x4 o = xv - sum * (1.f / 25.f);
    ushort4 ov;
    ov.x = f2b(o.x); ov.y = f2b(o.y); ov.z = f2b(o.z); ov.w = f2b(o.w);
    ob[l * 128] = ov;
    int ia = l + 13 > 511 ? 511 : l + 13;
    int ir = l - 12 < 0 ? 0 : l - 12;
    sum += b4f(xb[ia * 128]) - b4f(xb[ir * 128]);
  }
}

__global__ void k_lnstats(const u16* __restrict__ x, float* __restrict__ mu,
                          float* __restrict__ rs)
{
  int row = blockIdx.x;
  const u16* xr = x + (size_t)row * 512;
  int t = threadIdx.x;
  ushort2 p = ((const ushort2*)xr)[t];
  float v0 = b2f(p.x), v1 = b2f(p.y);
  float s = v0 + v1, ss = v0 * v0 + v1 * v1;
#pragma unroll
  for (int off = 32; off; off >>= 1) {
    s += __shfl_down(s, off);
    ss += __shfl_down(ss, off);
  }
  __shared__ float as[4], ass[4];
  if ((t & 63) == 0) { as[t >> 6] = s; ass[t >> 6] = ss; }
  __syncthreads();
  if (t == 0) {
    float S = as[0] + as[1] + as[2] + as[3];
    float SS = ass[0] + ass[1] + ass[2] + ass[3];
    float m = S * (1.f / 512.f);
    float var = SS * (1.f / 512.f) - m * m;
    mu[row] = m;
    rs[row] = rsqrtf(var + 1e-5f);
  }
}

// lastcat pass 1: partial[b][g][d] = sum_{l in g*64..} (x-mu)*rs  (512 blocks)
__global__ void k_lastcat1(const u16* __restrict__ x, const float* __restrict__ mu,
                           const float* __restrict__ rs, float* __restrict__ part)
{
  int b = blockIdx.x >> 3, g = blockIdx.x & 7, t = threadIdx.x;
  const u16* xb = x + (size_t)b * 262144;
  const float* mub = mu + b * 512;
  const float* rsb = rs + b * 512;
  float a0 = 0.f, a1 = 0.f;
#pragma unroll 4
  for (int l = g * 64; l < g * 64 + 64; ++l) {
    float m = mub[l], rr = rsb[l];
    ushort2 p = ((const ushort2*)(xb + l * 512))[t];
    a0 += (b2f(p.x) - m) * rr;
    a1 += (b2f(p.y) - m) * rr;
  }
  part[((size_t)b * 8 + g) * 512 + 2 * t]     = a0;
  part[((size_t)b * 8 + g) * 512 + 2 * t + 1] = a1;
}

// lastcat pass 2: cat[b][d] = nw[d]*(ln_last - mean_l);  norm_b cancels.
__global__ void k_lastcat2(const u16* __restrict__ x, const float* __restrict__ mu,
                           const float* __restrict__ rs, const float* __restrict__ part,
                           const float* __restrict__ nw, u16* __restrict__ cat)
{
  int b = blockIdx.x, t = threadIdx.x;
#pragma unroll
  for (int hh = 0; hh < 2; ++hh) {
    int d = t + hh * 256;
    float acc = 0.f;
#pragma unroll
    for (int g = 0; g < 8; ++g)
      acc += part[((size_t)b * 8 + g) * 512 + d];
    float lastv = (b2f(x[(size_t)b * 262144 + 511 * 512 + d]) - mu[b * 512 + 511])
                  * rs[b * 512 + 511];
    cat[b * 544 + d] = f2b(nw[d] * (lastv - acc * (1.f / 512.f)));
  }
}

__global__ void k_timecat(const float* __restrict__ tv, u16* __restrict__ cat)
{
  int id = blockIdx.x * 256 + threadIdx.x;  // 64*32
  if (id >= 2048) return;
  int b = id >> 5, j = id & 31;
  int pos = 512 + j;
  float v = (pos < 536) ? tv[((size_t)b * 512 + 511) * 24 + (pos - 512)] : 0.f;
  cat[b * 544 + pos] = f2b(v);
}

// ---------------------------------------------------------------------------
extern "C" void kernel_launch(void* const* d_in, const int* in_sizes, int n_in,
                              void* d_out, int out_size, void* d_ws, size_t ws_size,
                              hipStream_t stream)
{
  (void)in_sizes; (void)n_in; (void)out_size; (void)ws_size;
  const int*   x_app  = (const int*)  d_in[0];
  const float* x_time = (const float*)d_in[1];
  const float* tvec   = (const float*)d_in[2];
  // d_in[3] targets: unused by reference output
  const float* emb    = (const float*)d_in[4];
  const float* time_w = (const float*)d_in[5];
  const float* time_b = (const float*)d_in[6];
  const float* Wq     = (const float*)d_in[7];
  const float* bq     = (const float*)d_in[8];
  const float* Wo     = (const float*)d_in[9];
  const float* bo     = (const float*)d_in[10];
  const float* fwr    = (const float*)d_in[11];
  const float* fwi    = (const float*)d_in[12];
  const float* c1     = (const float*)d_in[13];
  const float* c2     = (const float*)d_in[14];
  const float* norm_w = (const float*)d_in[15];
  // d_in[16] norm_b: cancels in (xh - mean_l xh)
  const float* proj_w = (const float*)d_in[17];
  const float* proj_b = (const float*)d_in[18];
  float* out = (float*)d_out;

  char* w = (char*)d_ws;
  auto alloc = [&](size_t bytes) -> char* {
    char* p = w;
    w += (bytes + 255) & ~(size_t)255;
    return p;
  };
  // Workspace ~147 MB (was 244; fp32 Ax/Bs deleted)
  u16*   Cb   = (u16*)  alloc(33554432);          // x / x1 / x2 bf16
  u16*   YqT  = (u16*)  alloc(33554432);          // qT / fourier-out / conv1-out
  u16*   T1b  = (u16*)  alloc(33554432);          // t1 / t2 bf16
  float* S1   = (float*)alloc(8388608);           // spec (B,64,D) fp32
  u16*   Coef = (u16*)  alloc(4194304);           // mixed spectrum bf16
  float* wrT  = (float*)alloc(2 * 1048576 * 4);   // mix weights transposed
  float* wiT  = (float*)alloc(2 * 1048576 * 4);
  u16*   wqb  = (u16*)  alloc(2 * 262144 * 2);
  u16*   wob  = (u16*)  alloc(2 * 262144 * 2);
  u16*   c1b  = (u16*)  alloc(2 * 1048576 * 2);
  u16*   c2b  = (u16*)  alloc(2 * 1048576 * 2);
  u16*   pwb  = (u16*)  alloc(10000 * 544 * 2);
  u16*   dftB = (u16*)  alloc(64 * 512 * 2);
  u16*   Binv = (u16*)  alloc(512 * 64 * 2);
  float* muB  = (float*)alloc(131072);
  float* rsB  = (float*)alloc(131072);
  float* part = (float*)alloc(64 * 8 * 512 * 4);  // lastcat partials
  u16*   cat  = (u16*)  alloc(64 * 544 * 2);

  k_basis<<<128, 256, 0, stream>>>(dftB, Binv);
  k_transp<<<1024, 256, 0, stream>>>(fwr, fwi, wrT, wiT);
  k_convert<<<2048, 256, 0, stream>>>(Wq, wqb, 524288);
  k_convert<<<2048, 256, 0, stream>>>(Wo, wob, 524288);
  k_convert<<<8192, 256, 0, stream>>>(c1, c1b, 2097152);
  k_convert<<<8192, 256, 0, stream>>>(c2, c2b, 2097152);
  k_convproj<<<21250, 256, 0, stream>>>(proj_w, pwb);
  k_embed<<<16384, 256, 0, stream>>>(x_app, x_time, emb, time_w, time_b, Cb);

  for (int l = 0; l < 2; ++l) {
    const u16* wq_l = wqb + l * 262144;
    const u16* wo_l = wob + l * 262144;
    const u16* c1_l = c1b + l * 1048576;
    const u16* c2_l = c2b + l * 1048576;

    // qT[b][d][l] = (x @ Wq^T + bq)^T, bf16, batched over b, TRANS store
    k_gemm<true, false, false, true, false, true, false>
        <<<dim3(4, 4, 64), 256, 0, stream>>>(
        Cb, wq_l, bq + l * 512, nullptr, nullptr, YqT, 512, 512, 512,
        262144, 0, 262144, 0, 0);
    // spec[b][m][d] = qT[b] @ dftB^T  (M=512,N=64 pad 128,K=512), TRANS store
    k_gemm<false, false, false, false, true, true, false>
        <<<dim3(1, 4, 64), 256, 0, stream>>>(
        YqT, dftB, nullptr, nullptr, S1, nullptr, 512, 64, 512,
        262144, 0, 32768, 0, 0);
    k_mix<<<dim3(256, 4), 256, 0, stream>>>(
        S1, wrT + l * 1048576, wiT + l * 1048576, Coef);
    // inverse DFT as GEMM: YqT[b*512+d][l] = Coef @ Binv^T (M=32768,N=512,K=64)
    k_gemm<false, false, false, true, false, false, true>
        <<<dim3(1024, 1, 1), 256, 0, stream>>>(
        Coef, Binv, nullptr, nullptr, nullptr, YqT, 32768, 512, 64,
        0, 0, 0, 4, 256);
    // t1 = fourier_reshaped @ Wo^T + bo + x   (res = Cb bf16) -> T1b bf16
    k_gemm<true, false, true, true, false, false, true>
        <<<dim3(1024, 1, 1), 256, 0, stream>>>(
        YqT, wo_l, bo + l * 512, Cb, nullptr, T1b, 32768, 512, 512,
        0, 0, 0, 4, 256);
    k_decomp<<<512, 256, 0, stream>>>(T1b, Cb);     // x1 bf16
    for (int ch = 0; ch < 4; ++ch) {
      const size_t eo = (size_t)ch * 8192 * 512;
      // y = relu(x1 @ c1^T) -> bf16
      k_gemm<false, true, false, true, false, false, true>
          <<<dim3(1024, 1, 1), 256, 0, stream>>>(
          Cb + eo, c1_l, nullptr, nullptr, nullptr, YqT, 8192, 2048, 512,
          0, 0, 0, 16, 64);
      // t2 = y @ c2^T + x1  (res = Cb bf16) -> T1b bf16
      k_gemm<false, false, true, true, false, false, true>
          <<<dim3(256, 1, 1), 256, 0, stream>>>(
          YqT, c2_l, nullptr, Cb + eo, nullptr, T1b + eo, 8192, 512, 2048,
          0, 0, 0, 4, 64);
    }
    k_decomp<<<512, 256, 0, stream>>>(T1b, Cb);     // next-layer x bf16
  }

  k_lnstats<<<32768, 256, 0, stream>>>(Cb, muB, rsB);
  k_lastcat1<<<512, 256, 0, stream>>>(Cb, muB, rsB, part);
  k_lastcat2<<<64, 256, 0, stream>>>(Cb, muB, rsB, part, norm_w, cat);
  k_timecat<<<8, 256, 0, stream>>>(tvec, cat);
  // score = cat @ proj_w^T + proj_b   (K padded 536->544 with zeros)
  k_gemm<true, false, false, false, true, false, false>
      <<<dim3(79, 1, 1), 256, 0, stream>>>(
      cat, pwb, proj_b, nullptr, out, nullptr, 64, 10000, 544,
      0, 0, 0, 0, 0);
}

// Round 11
// 971.399 us; speedup vs baseline: 2.2763x; 2.2763x over previous
//
#include <hip/hip_runtime.h>

// ---------------------------------------------------------------------------
// AppUsageFEDformer forward on MI355X (gfx950).
// embed -> 2x [Wq gemm(->qT bf16) -> DFT-GEMM -> mix -> iDFT-GEMM ->
//              Wo gemm(+res) -> decomp -> conv1(relu) -> conv2(+res) -> decomp]
//          -> layernorm(+L-mean sub) -> last-token concat -> proj gemm.
// R10->R11: k_gemm reverted to the R9-proven SCALAR-register 1-deep pipeline.
// R8/R10's 2-deep "register" pipeline actually kept its uint4[2] staging
// arrays ON STACK (lambda by-ref capture defeated mem2reg): 64B scratch
// store+load per thread per K-iter = the observed +258MB WRITE, 115us GEMMs.
// Scalars va0..vb1 are register-proven (R9: <=51us, WRITE 65MB, VGPR 56).
// KEPT from R10: full bf16 activation chain (absmax 9.77e-3, 4x margin),
// bf16-io k_decomp w/ XCD-grouped swizzle, 147MB workspace.
// ---------------------------------------------------------------------------

typedef unsigned short u16;
typedef float f32x4 __attribute__((ext_vector_type(4)));
typedef __bf16 bf16x8 __attribute__((ext_vector_type(8)));

__device__ __forceinline__ u16 f2b(float f) {
  unsigned u = __float_as_uint(f);
  return (u16)((u + 0x7FFFu + ((u >> 16) & 1u)) >> 16);
}
__device__ __forceinline__ float b2f(u16 v) {
  return __uint_as_float((unsigned)v << 16);
}
__device__ __forceinline__ f32x4 b4f(ushort4 v) {
  f32x4 r;
  r.x = b2f(v.x); r.y = b2f(v.y); r.z = b2f(v.z); r.w = b2f(v.w);
  return r;
}

// ---------------- bf16 MFMA GEMM:  C = A(MxK) * B(NxK)^T (+bias)(+res)(relu)
// 128x128 tile, BK=32.  Thread t stages 16B of A and B rows r0=t>>2, r0+64
// (coalesced 1KB/wave) in SCALAR uint4 regs for one iteration, ds_writes
// with XOR bank swizzle, one barrier/iter (drains lgkm only, not the
// in-flight global loads).  R7/R9-verified: 0 conflicts, no scratch.
template<bool BIAS, bool RELU, bool RES, bool OUTBF16, bool GUARD, bool TRANS,
         bool SWZ>
__global__ __launch_bounds__(256, 3)
void k_gemm(const u16* __restrict__ A, const u16* __restrict__ B,
            const float* __restrict__ bias, const u16* __restrict__ res,
            float* __restrict__ Cf, u16* __restrict__ Cb,
            int M, int N, int K,
            long zA, long zB, long zC, int nbn, int nbm)
{
  __shared__ __align__(16) u16 sA[2][128 * 32];
  __shared__ __align__(16) u16 sB[2][128 * 32];
  const int tid = threadIdx.x;
  const int wave = tid >> 6, lane = tid & 63;
  int bn, bm;
  if (SWZ) {
    int bid = blockIdx.x;
    int xcd = bid & 7, loc = bid >> 3;
    bn = loc % nbn;
    bm = xcd * (nbm >> 3) + loc / nbn;
  } else {
    bn = blockIdx.x;
    bm = blockIdx.y;
  }
  const int bz = blockIdx.z;
  const int wm = (wave >> 1) * 64, wn = (wave & 1) * 64;

  A += (size_t)bz * zA;
  B += (size_t)bz * zB;

  const int r0 = tid >> 2;              // row 0..63 (row1 = r0+64)
  const int lg = tid & 3;               // logical 16B group
  const int ps = lg ^ ((r0 >> 1) & 3);  // physical group (same for r0,r0+64)
  int gmA0 = bm * 128 + r0, gmA1 = gmA0 + 64;
  int gnB0 = bn * 128 + r0, gnB1 = gnB0 + 64;
  if (GUARD) {
    gmA0 = gmA0 < M ? gmA0 : M - 1;
    gmA1 = gmA1 < M ? gmA1 : M - 1;
    gnB0 = gnB0 < N ? gnB0 : N - 1;
    gnB1 = gnB1 < N ? gnB1 : N - 1;
  }
  const size_t rb = (size_t)K * 2;
  const char* pa0 = (const char*)A + (size_t)gmA0 * rb + lg * 16;
  const char* pa1 = (const char*)A + (size_t)gmA1 * rb + lg * 16;
  const char* pb0 = (const char*)B + (size_t)gnB0 * rb + lg * 16;
  const char* pb1 = (const char*)B + (size_t)gnB1 * rb + lg * 16;
  const int w0 = r0 * 32 + ps * 8;      // u16 offset in tile; row1 at +2048

  f32x4 acc[4][4];
  const f32x4 z = {0.f, 0.f, 0.f, 0.f};
#pragma unroll
  for (int i = 0; i < 4; ++i)
#pragma unroll
    for (int j = 0; j < 4; ++j) acc[i][j] = z;

  const int r = lane & 15, qd = lane >> 4;
  const int pA = (qd ^ ((lane >> 1) & 3)) * 8;   // fragment physical group
  const int nk = K >> 5;

  uint4 va0, va1, vb0, vb1;             // tile staged in SCALAR registers
  auto gload = [&](int kt) {
    const size_t ko = (size_t)kt * 64;
    va0 = *(const uint4*)(pa0 + ko);
    va1 = *(const uint4*)(pa1 + ko);
    vb0 = *(const uint4*)(pb0 + ko);
    vb1 = *(const uint4*)(pb1 + ko);
  };

  gload(0);
  int pg = 0;
  for (int kt = 0; kt < nk; ++kt) {
    // commit staged tile kt to LDS (waits vmcnt on va*/vb* only)
    *(uint4*)&sA[pg][w0]        = va0;
    *(uint4*)&sA[pg][w0 + 2048] = va1;
    *(uint4*)&sB[pg][w0]        = vb0;
    *(uint4*)&sB[pg][w0 + 2048] = vb1;
    if (kt + 1 < nk) gload(kt + 1);   // next tile flies during MFMA below
    __syncthreads();                  // drains lgkm (ds_write), not vmcnt
    bf16x8 af[4], bg[4];
#pragma unroll
    for (int mi = 0; mi < 4; ++mi)
      af[mi] = *(const bf16x8*)&sA[pg][(wm + mi * 16 + r) * 32 + pA];
#pragma unroll
    for (int ni = 0; ni < 4; ++ni)
      bg[ni] = *(const bf16x8*)&sB[pg][(wn + ni * 16 + r) * 32 + pA];
#pragma unroll
    for (int mi = 0; mi < 4; ++mi)
#pragma unroll
      for (int ni = 0; ni < 4; ++ni)
        acc[mi][ni] = __builtin_amdgcn_mfma_f32_16x16x32_bf16(
            af[mi], bg[ni], acc[mi][ni], 0, 0, 0);
    pg ^= 1;
  }

  if (Cf) Cf += (size_t)bz * zC;
  if (Cb) Cb += (size_t)bz * zC;
#pragma unroll
  for (int mi = 0; mi < 4; ++mi) {
#pragma unroll
    for (int ni = 0; ni < 4; ++ni) {
#pragma unroll
      for (int e = 0; e < 4; ++e) {
        int gm = bm * 128 + wm + mi * 16 + qd * 4 + e;  // C/D: row=quad*4+reg
        int gn = bn * 128 + wn + ni * 16 + r;           //       col=lane&15
        if (GUARD && (gm >= M || gn >= N)) continue;
        float v = acc[mi][ni][e];
        if (BIAS) v += bias[gn];
        if (RES)  v += b2f(res[(size_t)gm * N + gn]);
        if (RELU) v = v > 0.f ? v : 0.f;
        size_t oi = TRANS ? ((size_t)gn * M + gm) : ((size_t)gm * N + gn);
        if (OUTBF16) Cb[oi] = f2b(v);
        else         Cf[oi] = v;
      }
    }
  }
}

// ---------------- misc small kernels ----------------
__global__ void k_basis(u16* __restrict__ dftB, u16* __restrict__ Binv)
{
  int id = blockIdx.x * 256 + threadIdx.x;  // 32768
  if (id >= 32768) return;
  {
    int m = id >> 9, l = id & 511;
    int mm = m & 31;
    float ang = (float)((l * mm) & 511) * (6.283185307179586f / 512.f);
    float s, c;
    __sincosf(ang, &s, &c);
    dftB[id] = f2b(m < 32 ? c : -s);
  }
  {
    int l = id >> 6, m = id & 63;
    int mm = m & 31;
    float ang = (float)((l * mm) & 511) * (6.283185307179586f / 512.f);
    float s, c;
    __sincosf(ang, &s, &c);
    float v;
    if (m < 32) v = (m == 0 ? 1.f : 2.f) * (1.f / 512.f) * c;
    else        v = (mm == 0 ? 0.f : (-2.f / 512.f) * s);
    Binv[id] = f2b(v);
  }
}

__global__ void k_convert(const float* __restrict__ in, u16* __restrict__ out, int n)
{
  int id = blockIdx.x * 256 + threadIdx.x;
  if (id < n) out[id] = f2b(in[id]);
}

__global__ void k_convproj(const float* __restrict__ w, u16* __restrict__ o)
{
  int id = blockIdx.x * 256 + threadIdx.x;  // 10000*544
  if (id >= 10000 * 544) return;
  int n = id / 544, k = id % 544;
  o[id] = f2b(k < 536 ? w[(size_t)n * 536 + k] : 0.f);
}

// weight transpose for mode mix: wrT[((l*8+h)*32+m)][i][o], LDS pad 33.
__global__ void k_transp(const float* __restrict__ wr, const float* __restrict__ wi,
                         float* __restrict__ wrT, float* __restrict__ wiT)
{
  __shared__ float tr[64 * 33], ti[64 * 33];
  int blk = blockIdx.x;            // (l*8+h)*64+i, 1024 blocks
  int t = threadIdx.x;
  int lh = blk >> 6, i = blk & 63;
  const size_t src = (size_t)blk * 2048;   // o*32+m slab
#pragma unroll
  for (int p = 0; p < 8; ++p) {
    int id = p * 256 + t;
    int o = id >> 5, m = id & 31;
    tr[o * 33 + m] = wr[src + id];
    ti[o * 33 + m] = wi[src + id];
  }
  __syncthreads();
#pragma unroll
  for (int p = 0; p < 8; ++p) {
    int id = p * 256 + t;
    int m = id >> 6, o = id & 63;
    size_t dst = ((size_t)(lh * 32 + m) * 64 + i) * 64 + o;
    wrT[dst] = tr[o * 33 + m];
    wiT[dst] = ti[o * 33 + m];
  }
}

__global__ void k_embed(const int* __restrict__ xapp, const float* __restrict__ xtime,
                        const float* __restrict__ emb, const float* __restrict__ tw,
                        const float* __restrict__ tb, u16* __restrict__ xb)
{
  int id = blockIdx.x * 256 + threadIdx.x;  // B*L*128 (float4 lanes)
  int j = id & 127, bl = id >> 7;
  float4 e = ((const float4*)emb)[(size_t)xapp[bl] * 128 + j];
  float t = xtime[bl];
  float4 w4 = ((const float4*)tw)[j];
  float4 b4 = ((const float4*)tb)[j];
  ushort4 o;
  o.x = f2b(e.x + t * w4.x + b4.x);
  o.y = f2b(e.y + t * w4.y + b4.y);
  o.z = f2b(e.z + t * w4.z + b4.z);
  o.w = f2b(e.w + t * w4.w + b4.w);
  ((ushort4*)xb)[id] = o;
}

// mode mix: coef[b*512 + h*64+o][m](Re) / [32+m](Im), bf16 A-operand.
__global__ __launch_bounds__(256)
void k_mix(const float* __restrict__ spec, const float* __restrict__ wrT,
           const float* __restrict__ wiT, u16* __restrict__ Ab)
{
  __shared__ float swr[4096], swi[4096];   // [i*64+o]
  __shared__ float sre[4][64], sim[4][64]; // [bsub][i]
  int hm = blockIdx.x;                     // h*32+m
  int bg = blockIdx.y;                     // 0..3
  int h = hm >> 5, m = hm & 31, t = threadIdx.x;
  const float* wrb = wrT + (size_t)hm * 4096;
  const float* wib = wiT + (size_t)hm * 4096;
#pragma unroll
  for (int p = 0; p < 16; ++p) {
    int id = p * 256 + t;
    swr[id] = wrb[id];
    swi[id] = wib[id];
  }
  int o = t & 63, bsub = t >> 6;
  for (int b0 = 0; b0 < 16; b0 += 4) {
    __syncthreads();
    int b = bg * 16 + b0 + bsub;
    const float* spb = spec + (size_t)b * 32768;
    sre[bsub][o] = spb[m * 512 + h * 64 + o];
    sim[bsub][o] = spb[(32 + m) * 512 + h * 64 + o];
    __syncthreads();
    float aR = 0.f, aI = 0.f;
#pragma unroll 8
    for (int i = 0; i < 64; ++i) {
      float xr = sre[bsub][i], xi = sim[bsub][i];
      float wrv = swr[i * 64 + o], wiv = swi[i * 64 + o];
      aR += xr * wrv - xi * wiv;
      aI += xr * wiv + xi * wrv;
    }
    size_t row = (size_t)b * 512 + h * 64 + o;
    Ab[row * 64 + m] = f2b(aR);
    Ab[row * 64 + 32 + m] = f2b(aI);
  }
}

// series_decomp: out = x - movavg_25(x), edge-padded.  bf16 in/out, fp32
// accumulate.  XCD-grouped: all blocks of batch b run on XCD b%8,
// temporally clustered, so chunk-window overlap hits that XCD's L2.
__global__ void k_decomp(const u16* __restrict__ in, u16* __restrict__ outb)
{
  int blk = blockIdx.x;                 // 512 blocks
  int j = blk >> 3;
  int b = (blk & 7) + 8 * (j >> 3);     // xcd = b%8
  int ck = (j & 7) * 2 + (threadIdx.x >> 7);
  int d4 = threadIdx.x & 127;
  const ushort4* xb = (const ushort4*)(in + (size_t)b * 262144) + d4;
  ushort4* ob = (ushort4*)(outb + (size_t)b * 262144) + d4;
  int l0 = ck * 32;
  f32x4 sum = {0.f, 0.f, 0.f, 0.f};
#pragma unroll
  for (int jj = -12; jj <= 12; ++jj) {
    int idx = l0 + jj;
    idx = idx < 0 ? 0 : idx;
    sum += b4f(xb[idx * 128]);
  }
#pragma unroll 4
  for (int l = l0; l < l0 + 32; ++l) {
    f32x4 xv = b4f(xb[l * 128]);
    f32x4 o = xv - sum * (1.f / 25.f);
    ushort4 ov;
    ov.x = f2b(o.x); ov.y = f2b(o.y); ov.z = f2b(o.z); ov.w = f2b(o.w);
    ob[l * 128] = ov;
    int ia = l + 13 > 511 ? 511 : l + 13;
    int ir = l - 12 < 0 ? 0 : l - 12;
    sum += b4f(xb[ia * 128]) - b4f(xb[ir * 128]);
  }
}

__global__ void k_lnstats(const u16* __restrict__ x, float* __restrict__ mu,
                          float* __restrict__ rs)
{
  int row = blockIdx.x;
  const u16* xr = x + (size_t)row * 512;
  int t = threadIdx.x;
  ushort2 p = ((const ushort2*)xr)[t];
  float v0 = b2f(p.x), v1 = b2f(p.y);
  float s = v0 + v1, ss = v0 * v0 + v1 * v1;
#pragma unroll
  for (int off = 32; off; off >>= 1) {
    s += __shfl_down(s, off);
    ss += __shfl_down(ss, off);
  }
  __shared__ float as[4], ass[4];
  if ((t & 63) == 0) { as[t >> 6] = s; ass[t >> 6] = ss; }
  __syncthreads();
  if (t == 0) {
    float S = as[0] + as[1] + as[2] + as[3];
    float SS = ass[0] + ass[1] + ass[2] + ass[3];
    float m = S * (1.f / 512.f);
    float var = SS * (1.f / 512.f) - m * m;
    mu[row] = m;
    rs[row] = rsqrtf(var + 1e-5f);
  }
}

// lastcat pass 1: partial[b][g][d] = sum_{l in g*64..} (x-mu)*rs  (512 blocks)
__global__ void k_lastcat1(const u16* __restrict__ x, const float* __restrict__ mu,
                           const float* __restrict__ rs, float* __restrict__ part)
{
  int b = blockIdx.x >> 3, g = blockIdx.x & 7, t = threadIdx.x;
  const u16* xb = x + (size_t)b * 262144;
  const float* mub = mu + b * 512;
  const float* rsb = rs + b * 512;
  float a0 = 0.f, a1 = 0.f;
#pragma unroll 4
  for (int l = g * 64; l < g * 64 + 64; ++l) {
    float m = mub[l], rr = rsb[l];
    ushort2 p = ((const ushort2*)(xb + l * 512))[t];
    a0 += (b2f(p.x) - m) * rr;
    a1 += (b2f(p.y) - m) * rr;
  }
  part[((size_t)b * 8 + g) * 512 + 2 * t]     = a0;
  part[((size_t)b * 8 + g) * 512 + 2 * t + 1] = a1;
}

// lastcat pass 2: cat[b][d] = nw[d]*(ln_last - mean_l);  norm_b cancels.
__global__ void k_lastcat2(const u16* __restrict__ x, const float* __restrict__ mu,
                           const float* __restrict__ rs, const float* __restrict__ part,
                           const float* __restrict__ nw, u16* __restrict__ cat)
{
  int b = blockIdx.x, t = threadIdx.x;
#pragma unroll
  for (int hh = 0; hh < 2; ++hh) {
    int d = t + hh * 256;
    float acc = 0.f;
#pragma unroll
    for (int g = 0; g < 8; ++g)
      acc += part[((size_t)b * 8 + g) * 512 + d];
    float lastv = (b2f(x[(size_t)b * 262144 + 511 * 512 + d]) - mu[b * 512 + 511])
                  * rs[b * 512 + 511];
    cat[b * 544 + d] = f2b(nw[d] * (lastv - acc * (1.f / 512.f)));
  }
}

__global__ void k_timecat(const float* __restrict__ tv, u16* __restrict__ cat)
{
  int id = blockIdx.x * 256 + threadIdx.x;  // 64*32
  if (id >= 2048) return;
  int b = id >> 5, j = id & 31;
  int pos = 512 + j;
  float v = (pos < 536) ? tv[((size_t)b * 512 + 511) * 24 + (pos - 512)] : 0.f;
  cat[b * 544 + pos] = f2b(v);
}

// ---------------------------------------------------------------------------
extern "C" void kernel_launch(void* const* d_in, const int* in_sizes, int n_in,
                              void* d_out, int out_size, void* d_ws, size_t ws_size,
                              hipStream_t stream)
{
  (void)in_sizes; (void)n_in; (void)out_size; (void)ws_size;
  const int*   x_app  = (const int*)  d_in[0];
  const float* x_time = (const float*)d_in[1];
  const float* tvec   = (const float*)d_in[2];
  // d_in[3] targets: unused by reference output
  const float* emb    = (const float*)d_in[4];
  const float* time_w = (const float*)d_in[5];
  const float* time_b = (const float*)d_in[6];
  const float* Wq     = (const float*)d_in[7];
  const float* bq     = (const float*)d_in[8];
  const float* Wo     = (const float*)d_in[9];
  const float* bo     = (const float*)d_in[10];
  const float* fwr    = (const float*)d_in[11];
  const float* fwi    = (const float*)d_in[12];
  const float* c1     = (const float*)d_in[13];
  const float* c2     = (const float*)d_in[14];
  const float* norm_w = (const float*)d_in[15];
  // d_in[16] norm_b: cancels in (xh - mean_l xh)
  const float* proj_w = (const float*)d_in[17];
  const float* proj_b = (const float*)d_in[18];
  float* out = (float*)d_out;

  char* w = (char*)d_ws;
  auto alloc = [&](size_t bytes) -> char* {
    char* p = w;
    w += (bytes + 255) & ~(size_t)255;
    return p;
  };
  // Workspace ~147 MB
  u16*   Cb   = (u16*)  alloc(33554432);          // x / x1 / x2 bf16
  u16*   YqT  = (u16*)  alloc(33554432);          // qT / fourier-out / conv1-out
  u16*   T1b  = (u16*)  alloc(33554432);          // t1 / t2 bf16
  float* S1   = (float*)alloc(8388608);           // spec (B,64,D) fp32
  u16*   Coef = (u16*)  alloc(4194304);           // mixed spectrum bf16
  float* wrT  = (float*)alloc(2 * 1048576 * 4);   // mix weights transposed
  float* wiT  = (float*)alloc(2 * 1048576 * 4);
  u16*   wqb  = (u16*)  alloc(2 * 262144 * 2);
  u16*   wob  = (u16*)  alloc(2 * 262144 * 2);
  u16*   c1b  = (u16*)  alloc(2 * 1048576 * 2);
  u16*   c2b  = (u16*)  alloc(2 * 1048576 * 2);
  u16*   pwb  = (u16*)  alloc(10000 * 544 * 2);
  u16*   dftB = (u16*)  alloc(64 * 512 * 2);
  u16*   Binv = (u16*)  alloc(512 * 64 * 2);
  float* muB  = (float*)alloc(131072);
  float* rsB  = (float*)alloc(131072);
  float* part = (float*)alloc(64 * 8 * 512 * 4);  // lastcat partials
  u16*   cat  = (u16*)  alloc(64 * 544 * 2);

  k_basis<<<128, 256, 0, stream>>>(dftB, Binv);
  k_transp<<<1024, 256, 0, stream>>>(fwr, fwi, wrT, wiT);
  k_convert<<<2048, 256, 0, stream>>>(Wq, wqb, 524288);
  k_convert<<<2048, 256, 0, stream>>>(Wo, wob, 524288);
  k_convert<<<8192, 256, 0, stream>>>(c1, c1b, 2097152);
  k_convert<<<8192, 256, 0, stream>>>(c2, c2b, 2097152);
  k_convproj<<<21250, 256, 0, stream>>>(proj_w, pwb);
  k_embed<<<16384, 256, 0, stream>>>(x_app, x_time, emb, time_w, time_b, Cb);

  for (int l = 0; l < 2; ++l) {
    const u16* wq_l = wqb + l * 262144;
    const u16* wo_l = wob + l * 262144;
    const u16* c1_l = c1b + l * 1048576;
    const u16* c2_l = c2b + l * 1048576;

    // qT[b][d][l] = (x @ Wq^T + bq)^T, bf16, batched over b, TRANS store
    k_gemm<true, false, false, true, false, true, false>
        <<<dim3(4, 4, 64), 256, 0, stream>>>(
        Cb, wq_l, bq + l * 512, nullptr, nullptr, YqT, 512, 512, 512,
        262144, 0, 262144, 0, 0);
    // spec[b][m][d] = qT[b] @ dftB^T  (M=512,N=64 pad 128,K=512), TRANS store
    k_gemm<false, false, false, false, true, true, false>
        <<<dim3(1, 4, 64), 256, 0, stream>>>(
        YqT, dftB, nullptr, nullptr, S1, nullptr, 512, 64, 512,
        262144, 0, 32768, 0, 0);
    k_mix<<<dim3(256, 4), 256, 0, stream>>>(
        S1, wrT + l * 1048576, wiT + l * 1048576, Coef);
    // inverse DFT as GEMM: YqT[b*512+d][l] = Coef @ Binv^T (M=32768,N=512,K=64)
    k_gemm<false, false, false, true, false, false, true>
        <<<dim3(1024, 1, 1), 256, 0, stream>>>(
        Coef, Binv, nullptr, nullptr, nullptr, YqT, 32768, 512, 64,
        0, 0, 0, 4, 256);
    // t1 = fourier_reshaped @ Wo^T + bo + x   (res = Cb bf16) -> T1b bf16
    k_gemm<true, false, true, true, false, false, true>
        <<<dim3(1024, 1, 1), 256, 0, stream>>>(
        YqT, wo_l, bo + l * 512, Cb, nullptr, T1b, 32768, 512, 512,
        0, 0, 0, 4, 256);
    k_decomp<<<512, 256, 0, stream>>>(T1b, Cb);     // x1 bf16
    for (int ch = 0; ch < 4; ++ch) {
      const size_t eo = (size_t)ch * 8192 * 512;
      // y = relu(x1 @ c1^T) -> bf16
      k_gemm<false, true, false, true, false, false, true>
          <<<dim3(1024, 1, 1), 256, 0, stream>>>(
          Cb + eo, c1_l, nullptr, nullptr, nullptr, YqT, 8192, 2048, 512,
          0, 0, 0, 16, 64);
      // t2 = y @ c2^T + x1  (res = Cb bf16) -> T1b bf16
      k_gemm<false, false, true, true, false, false, true>
          <<<dim3(256, 1, 1), 256, 0, stream>>>(
          YqT, c2_l, nullptr, Cb + eo, nullptr, T1b + eo, 8192, 512, 2048,
          0, 0, 0, 4, 64);
    }
    k_decomp<<<512, 256, 0, stream>>>(T1b, Cb);     // next-layer x bf16
  }

  k_lnstats<<<32768, 256, 0, stream>>>(Cb, muB, rsB);
  k_lastcat1<<<512, 256, 0, stream>>>(Cb, muB, rsB, part);
  k_lastcat2<<<64, 256, 0, stream>>>(Cb, muB, rsB, part, norm_w, cat);
  k_timecat<<<8, 256, 0, stream>>>(tvec, cat);
  // score = cat @ proj_w^T + proj_b   (K padded 536->544 with zeros)
  k_gemm<true, false, false, false, true, false, false>
      <<<dim3(79, 1, 1), 256, 0, stream>>>(
      cat, pwb, proj_b, nullptr, out, nullptr, 64, 10000, 544,
      0, 0, 0, 0, 0);
}